// Round 8
// baseline (274.278 us; speedup 1.0000x reference)
//
#include <hip/hip_runtime.h>
#include <hip/hip_fp16.h>

#define N_SYM 50000
#define N_DIS 10000
#define F_IN 128
#define HID 128
#define OUTF 64
#define NE 640000
#define NEG_SLOPE 0.2f

#define SPAN 512          // nodes per bin
#define NB 98             // ceil(N_SYM / SPAN)
#define SUBS 8            // sub-cursors per bin (blockIdx&7 ~ XCD round-robin)
#define SCAP 1280         // per (bin,sub) capacity: mean 816, +16 sigma
#define LCAP 48           // per-node bucket capacity: P(Poisson(12.8) > 48) ~ 1e-15

typedef _Float16 f16x8 __attribute__((ext_vector_type(8)));
typedef float f32x4 __attribute__((ext_vector_type(4)));

// ---- K1: blocks 0..624: h16 = fp16(x_dis @ Wsrc_ds) + al2 fused
//         block 625:      v_dst = Wdst_ds @ adst_ds + zero bin cursors
#define R1 16
__global__ __launch_bounds__(256) void k_proj(const float* __restrict__ x,
                                              const float* __restrict__ W,
                                              const float* __restrict__ asrc,
                                              const float* __restrict__ Wd,
                                              const float* __restrict__ ad,
                                              __half* __restrict__ h,
                                              float* __restrict__ al2,
                                              float* __restrict__ v_dst,
                                              int* __restrict__ bcur) {
    int tid = threadIdx.x;
    if (blockIdx.x == 625) {                  // v_dst = Wdst_ds @ adst_ds
        for (int i = tid; i < NB * SUBS; i += 256) bcur[i] = 0;
        int k = tid >> 1;                     // output 0..127
        int hh = tid & 1;
        const float4* Wr = (const float4*)(Wd + k * HID + hh * 64);
        const float4* av = (const float4*)(ad + hh * 64);
        float s = 0.f;
#pragma unroll
        for (int j = 0; j < 16; ++j) {
            float4 w = Wr[j], xx = av[j];
            s += w.x * xx.x + w.y * xx.y + w.z * xx.z + w.w * xx.w;
        }
        s += __shfl_xor(s, 1);
        if (!hh) v_dst[k] = s;
        return;
    }
    __shared__ float xl[R1 * F_IN];
    int rowbase = blockIdx.x * R1;
    const float4* src = (const float4*)(x + rowbase * F_IN);
    float4* dl = (float4*)xl;
    for (int i = tid; i < R1 * F_IN / 4; i += 256) dl[i] = src[i];
    __syncthreads();
    int c2 = tid & 63;   // column pair: cols 2*c2, 2*c2+1
    int rg = tid >> 6;   // 0..3 -> rows rg+4i
    float acc[4][2] = {};
    for (int k = 0; k < F_IN; ++k) {
        float2 w = *(const float2*)(W + k * HID + c2 * 2);
#pragma unroll
        for (int i = 0; i < 4; ++i) {
            float xv = xl[(rg + 4 * i) * F_IN + k];
            acc[i][0] += xv * w.x;
            acc[i][1] += xv * w.y;
        }
    }
    __half2* h2 = (__half2*)h;
    float2 av = *(const float2*)(asrc + 2 * c2);
#pragma unroll
    for (int i = 0; i < 4; ++i) {
        h2[(rowbase + rg + 4 * i) * 64 + c2] = __floats2half2_rn(acc[i][0], acc[i][1]);
        float p = acc[i][0] * av.x + acc[i][1] * av.y;   // al2 partial
#pragma unroll
        for (int m = 32; m; m >>= 1) p += __shfl_xor(p, m);
        if (c2 == 0) al2[rowbase + rg + 4 * i] = p;
    }
}

// ---- K2: ar2[i] = dot(x_sym[i,:], v_dst) (32 lanes/row)
//         + fused dense bin-scatter of edges (packed (slocal, d) in 4B)
__global__ __launch_bounds__(256) void k_ar(const float* __restrict__ h,
                                            const float* __restrict__ a,
                                            float* __restrict__ o,
                                            const int* __restrict__ esrc,
                                            const int* __restrict__ edst,
                                            int* __restrict__ bcur,
                                            unsigned int* __restrict__ bins) {
    int gid = blockIdx.x * 256 + threadIdx.x;
    if (gid < NE) {
        int s = esrc[gid];
        int d = edst[gid];
        int region = (s >> 9) * SUBS + (blockIdx.x & 7);
        unsigned int v = ((unsigned int)(s & 511) << 14) | (unsigned int)d;
        int pos = atomicAdd(&bcur[region], 1);
        if (pos < SCAP) bins[region * SCAP + pos] = v;
    }
    int r = gid >> 5;
    int l = threadIdx.x & 31;
    if (r >= N_SYM) return;
    float4 hv = *(const float4*)(h + r * F_IN + l * 4);
    float4 av = *(const float4*)(a + l * 4);
    float s = hv.x * av.x + hv.y * av.y + hv.z * av.z + hv.w * av.w;
#pragma unroll
    for (int m = 16; m; m >>= 1) s += __shfl_xor(s, m);
    if (!l) o[r] = s;
}

// ---- K3: per-bin LDS counting-bucket build -> coalesced bucket/deg writes
__global__ __launch_bounds__(256) void k_build(const unsigned int* __restrict__ bins,
                                               const int* __restrict__ bcur,
                                               unsigned short* __restrict__ bucket,
                                               int* __restrict__ deg) {
    __shared__ int lcount[SPAN];
    __shared__ unsigned short lb[SPAN * LCAP];   // 49 KB
    int tid = threadIdx.x;
    int bin = blockIdx.x;
    int nodebase = bin * SPAN;
    int nnodes = min(SPAN, N_SYM - nodebase);
    for (int i = tid; i < SPAN; i += 256) lcount[i] = 0;
    __syncthreads();
    for (int sub = 0; sub < SUBS; ++sub) {
        int region = bin * SUBS + sub;
        int n = bcur[region];
        if (n > SCAP) n = SCAP;
        const unsigned int* base = bins + region * SCAP;
        for (int i = tid; i < n; i += 256) {
            unsigned int v = base[i];
            int sl = v >> 14;
            int d = v & 0x3FFF;
            int rank = atomicAdd(&lcount[sl], 1);
            if (rank < LCAP) lb[sl * LCAP + rank] = (unsigned short)d;
        }
    }
    __syncthreads();
    for (int i = tid; i < nnodes; i += 256)
        deg[nodebase + i] = min(lcount[i], LCAP);
    // flat coalesced copy: lb -> bucket[nodebase*LCAP ..]
    unsigned int* gb = (unsigned int*)(bucket + nodebase * LCAP);
    const unsigned int* lbu = (const unsigned int*)lb;
    int words = nnodes * LCAP / 2;
    for (int i = tid; i < words; i += 256) gb[i] = lbu[i];
}

// ---- K4: per-node softmax + weighted gather: 32 lanes / node ----
__device__ __forceinline__ void acc_row(float4& acc, float2 rr, float ww) {
    __half2 a01 = *(__half2*)&rr.x;
    __half2 a23 = *(__half2*)&rr.y;
    float2 f01 = __half22float2(a01), f23 = __half22float2(a23);
    acc.x += ww * f01.x;
    acc.y += ww * f01.y;
    acc.z += ww * f23.x;
    acc.w += ww * f23.y;
}

__global__ __launch_bounds__(256) void k_agg(const int* __restrict__ deg,
                                             const unsigned short* __restrict__ bucket,
                                             const float* __restrict__ al2,
                                             const float* __restrict__ ar2,
                                             const __half* __restrict__ h16,
                                             const float* __restrict__ b,
                                             __half* __restrict__ hout) {
    int node = (blockIdx.x * 256 + threadIdx.x) >> 5;
    int l = threadIdx.x & 31;
    if (node >= N_SYM) return;
    int dg = deg[node];            // already clamped <= LCAP
    int off = node * LCAP;
    float arn = ar2[node];
    // lane l caches edge l's (dis, logit) in registers (coalesced load)
    int di = 0;
    float lv = -1e30f;
    if (l < dg) {
        di = bucket[off + l];
        float t = al2[di] + arn;
        lv = (t > 0.f) ? t : NEG_SLOPE * t;
    }
    float mm = lv;
    for (int i = 32 + l; i < dg; i += 32) {        // rare tail (dg in 33..48)
        float t = al2[bucket[off + i]] + arn;
        t = (t > 0.f) ? t : NEG_SLOPE * t;
        mm = fmaxf(mm, t);
    }
#pragma unroll
    for (int s = 16; s; s >>= 1) mm = fmaxf(mm, __shfl_xor(mm, s, 32));

    const float2* hb = (const float2*)h16;   // row d -> units d*32 + l
    float4 acc = make_float4(0.f, 0.f, 0.f, 0.f);
    float den = 0.f;                          // w lane-uniform: no reduce needed
    int dgc = dg < 32 ? dg : 32;
    int e = 0;
    for (; e + 4 <= dgc; e += 4) {
        int d0 = __shfl(di, e + 0, 32); float w0 = __expf(__shfl(lv, e + 0, 32) - mm);
        int d1 = __shfl(di, e + 1, 32); float w1 = __expf(__shfl(lv, e + 1, 32) - mm);
        int d2 = __shfl(di, e + 2, 32); float w2 = __expf(__shfl(lv, e + 2, 32) - mm);
        int d3 = __shfl(di, e + 3, 32); float w3 = __expf(__shfl(lv, e + 3, 32) - mm);
        float2 r0 = hb[d0 * 32 + l];
        float2 r1 = hb[d1 * 32 + l];
        float2 r2 = hb[d2 * 32 + l];
        float2 r3 = hb[d3 * 32 + l];
        den += w0 + w1 + w2 + w3;
        acc_row(acc, r0, w0);
        acc_row(acc, r1, w1);
        acc_row(acc, r2, w2);
        acc_row(acc, r3, w3);
    }
    for (; e < dgc; ++e) {
        int d = __shfl(di, e, 32);
        float w = __expf(__shfl(lv, e, 32) - mm);
        float2 r = hb[d * 32 + l];
        den += w;
        acc_row(acc, r, w);
    }
    for (int i = 32; i < dg; ++i) {               // rare tail (dg in 33..48)
        int dd = bucket[off + i];
        float t = al2[dd] + arn;
        t = (t > 0.f) ? t : NEG_SLOPE * t;
        float w = __expf(t - mm);
        float2 r = hb[dd * 32 + l];
        den += w;
        acc_row(acc, r, w);
    }
    float inv = (dg > 0) ? 1.f / den : 0.f;
    float4 bv = *(const float4*)(b + l * 4);
    __half2 o01 = __floats2half2_rn(fmaxf(acc.x * inv + bv.x, 0.f),
                                    fmaxf(acc.y * inv + bv.y, 0.f));
    __half2 o23 = __floats2half2_rn(fmaxf(acc.z * inv + bv.z, 0.f),
                                    fmaxf(acc.w * inv + bv.w, 0.f));
    float2 pack;
    *(__half2*)&pack.x = o01;
    *(__half2*)&pack.y = o23;
    *(float2*)((__half2*)hout + node * 64 + 2 * l) = pack;
}

// ---- out = h_sym(fp16) @ lin_W + lin_b via MFMA f16: 64 rows/block, 4 waves ----
__global__ __launch_bounds__(256) void k_final(const __half* __restrict__ h,
                                               const float* __restrict__ W,
                                               const float* __restrict__ b,
                                               float* __restrict__ out) {
    // W^T staged fp16, row stride 136 halves = 272 B (16B-aligned, 2-way bank max)
    __shared__ __align__(16) _Float16 BT[64][136];
    __shared__ float bias[64];
    int tid = threadIdx.x;
    for (int idx = tid; idx < HID * OUTF; idx += 256) {
        int k = idx >> 6, c = idx & 63;
        BT[c][k] = (_Float16)W[idx];
    }
    if (tid < 64) bias[tid] = b[tid];
    __syncthreads();
    int wave = tid >> 6, lane = tid & 63;
    int rowbase = blockIdx.x * 64 + wave * 16;
    int arow = rowbase + (lane & 15);
    if (arow >= N_SYM) arow = N_SYM - 1;          // clamp reads; stores guarded
    int kbase = (lane >> 4) * 8;
    const _Float16* hp = (const _Float16*)h;
    f16x8 a[4];
#pragma unroll
    for (int kc = 0; kc < 4; ++kc)
        a[kc] = *(const f16x8*)(hp + arow * HID + kc * 32 + kbase);
#pragma unroll
    for (int ct = 0; ct < 4; ++ct) {
        int bcol = ct * 16 + (lane & 15);
        f32x4 acc = {0.f, 0.f, 0.f, 0.f};
#pragma unroll
        for (int kc = 0; kc < 4; ++kc) {
            f16x8 bf = *(const f16x8*)(&BT[bcol][kc * 32 + kbase]);
            acc = __builtin_amdgcn_mfma_f32_16x16x32_f16(a[kc], bf, acc, 0, 0, 0);
        }
        int r0 = rowbase + (lane >> 4) * 4;
        float bc = bias[bcol];
#pragma unroll
        for (int r = 0; r < 4; ++r) {
            int row = r0 + r;
            if (row < N_SYM) out[row * OUTF + bcol] = acc[r] + bc;
        }
    }
}

extern "C" void kernel_launch(void* const* d_in, const int* in_sizes, int n_in,
                              void* d_out, int out_size, void* d_ws, size_t ws_size,
                              hipStream_t stream) {
    const float* x_sym   = (const float*)d_in[0];
    const float* x_dis   = (const float*)d_in[1];
    const int*   esrc    = (const int*)d_in[2];
    const int*   edst    = (const int*)d_in[3];
    // d_in[4..8] = sym->dis GAT params: DEAD CODE (h_dis never used)
    const float* Wsrc_ds = (const float*)d_in[9];
    const float* Wdst_ds = (const float*)d_in[10];
    const float* asrc_ds = (const float*)d_in[11];
    const float* adst_ds = (const float*)d_in[12];
    const float* b_ds    = (const float*)d_in[13];
    const float* lin_W   = (const float*)d_in[14];
    const float* lin_b   = (const float*)d_in[15];
    float* out = (float*)d_out;

    // workspace layout (~25 MB)
    float*  ws     = (float*)d_ws;
    float*  v_dst  = ws;                      // 128
    float*  al2    = v_dst + 128;             // N_DIS
    float*  ar2    = al2 + N_DIS;             // N_SYM
    int*    deg    = (int*)(ar2 + N_SYM);     // N_SYM
    int*    bcur   = deg + N_SYM;             // NB*SUBS (784) + pad to 1024
    unsigned int*   bins   = (unsigned int*)(bcur + 1024);     // NB*SUBS*SCAP (4 MB)
    unsigned short* bucket = (unsigned short*)(bins + NB * SUBS * SCAP); // N_SYM*LCAP (4.8 MB)
    __half* h16    = (__half*)(bucket + N_SYM * LCAP);         // N_DIS*HID (2.56 MB)
    __half* h_sym  = h16 + N_DIS * HID;       // N_SYM*HID halves (12.8 MB)

    k_proj<<<626, 256, 0, stream>>>(x_dis, Wsrc_ds, asrc_ds, Wdst_ds, adst_ds,
                                    h16, al2, v_dst, bcur);
    k_ar<<<N_SYM * 32 / 256, 256, 0, stream>>>(x_sym, v_dst, ar2, esrc, edst,
                                               bcur, bins);
    k_build<<<NB, 256, 0, stream>>>(bins, bcur, bucket, deg);
    k_agg<<<N_SYM * 32 / 256, 256, 0, stream>>>(deg, bucket, al2, ar2, h16,
                                                b_ds, h_sym);
    k_final<<<(N_SYM + 63) / 64, 256, 0, stream>>>(h_sym, lin_W, lin_b, out);
}

// Round 9
// 91.850 us; speedup vs baseline: 2.9862x; 2.9862x over previous
//
#include <hip/hip_runtime.h>
#include <hip/hip_fp16.h>

#define N_SYM 50000
#define N_DIS 10000
#define F_IN 128
#define HID 128
#define OUTF 64
#define NE 640000
#define NEG_SLOPE 0.2f

#define SPAN 128          // nodes per bin
#define NB 391            // ceil(N_SYM / SPAN)
#define SUBS 16           // sub-regions per bin (blockIdx&15: XCD-pure mod 8)
#define SCAP 192          // per-region capacity: mean 102, +8.9 sigma
#define CURSTRIDE 16      // ints: one cursor per 64B line (atomic line throughput!)
#define NREG (NB * SUBS)  // 6256 regions
#define LCAP 48           // per-node bucket capacity: P(Poisson(12.8)>48) ~ 1e-12

typedef _Float16 f16x8 __attribute__((ext_vector_type(8)));
typedef float f32x4 __attribute__((ext_vector_type(4)));

// ---- K1: blocks 0..624: h16 = fp16(x_dis @ Wsrc_ds) + al2 fused + cursor zero
//         block 625:      v_dst = Wdst_ds @ adst_ds
#define R1 16
__global__ __launch_bounds__(256) void k_proj(const float* __restrict__ x,
                                              const float* __restrict__ W,
                                              const float* __restrict__ asrc,
                                              const float* __restrict__ Wd,
                                              const float* __restrict__ ad,
                                              __half* __restrict__ h,
                                              float* __restrict__ al2,
                                              float* __restrict__ v_dst,
                                              int* __restrict__ bcur) {
    int tid = threadIdx.x;
    if (blockIdx.x == 625) {                  // v_dst = Wdst_ds @ adst_ds
        int k = tid >> 1;                     // output 0..127
        int hh = tid & 1;
        const float4* Wr = (const float4*)(Wd + k * HID + hh * 64);
        const float4* av = (const float4*)(ad + hh * 64);
        float s = 0.f;
#pragma unroll
        for (int j = 0; j < 16; ++j) {
            float4 w = Wr[j], xx = av[j];
            s += w.x * xx.x + w.y * xx.y + w.z * xx.z + w.w * xx.w;
        }
        s += __shfl_xor(s, 1);
        if (!hh) v_dst[k] = s;
        return;
    }
    int gid = blockIdx.x * 256 + tid;
    if (gid < NREG * CURSTRIDE) bcur[gid] = 0;   // fused cursor zero (160000 > 100096)
    __shared__ float xl[R1 * F_IN];
    int rowbase = blockIdx.x * R1;
    const float4* src = (const float4*)(x + rowbase * F_IN);
    float4* dl = (float4*)xl;
    for (int i = tid; i < R1 * F_IN / 4; i += 256) dl[i] = src[i];
    __syncthreads();
    int c2 = tid & 63;   // column pair: cols 2*c2, 2*c2+1
    int rg = tid >> 6;   // 0..3 -> rows rg+4i
    float acc[4][2] = {};
    for (int k = 0; k < F_IN; ++k) {
        float2 w = *(const float2*)(W + k * HID + c2 * 2);
#pragma unroll
        for (int i = 0; i < 4; ++i) {
            float xv = xl[(rg + 4 * i) * F_IN + k];
            acc[i][0] += xv * w.x;
            acc[i][1] += xv * w.y;
        }
    }
    __half2* h2 = (__half2*)h;
    float2 av = *(const float2*)(asrc + 2 * c2);
#pragma unroll
    for (int i = 0; i < 4; ++i) {
        h2[(rowbase + rg + 4 * i) * 64 + c2] = __floats2half2_rn(acc[i][0], acc[i][1]);
        float p = acc[i][0] * av.x + acc[i][1] * av.y;   // al2 partial
#pragma unroll
        for (int m = 32; m; m >>= 1) p += __shfl_xor(p, m);
        if (c2 == 0) al2[rowbase + rg + 4 * i] = p;
    }
}

// ---- K2: ar2[i] = dot(x_sym[i,:], v_dst) (32 lanes/row)
//         + fused dense bin-scatter (packed (s&127, d) in 4B), XCD-pure regions
__global__ __launch_bounds__(256) void k_ar(const float* __restrict__ h,
                                            const float* __restrict__ a,
                                            float* __restrict__ o,
                                            const int* __restrict__ esrc,
                                            const int* __restrict__ edst,
                                            int* __restrict__ bcur,
                                            unsigned int* __restrict__ bins) {
    int gid = blockIdx.x * 256 + threadIdx.x;
    if (gid < NE) {
        int s = esrc[gid];
        int d = edst[gid];
        int region = (s >> 7) * SUBS + (blockIdx.x & (SUBS - 1));
        unsigned int v = ((unsigned int)(s & 127) << 14) | (unsigned int)d;
        int pos = atomicAdd(&bcur[region * CURSTRIDE], 1);
        if (pos < SCAP) bins[region * SCAP + pos] = v;
    }
    int r = gid >> 5;
    int l = threadIdx.x & 31;
    if (r >= N_SYM) return;
    float4 hv = *(const float4*)(h + r * F_IN + l * 4);
    float4 av = *(const float4*)(a + l * 4);
    float s = hv.x * av.x + hv.y * av.y + hv.z * av.z + hv.w * av.w;
#pragma unroll
    for (int m = 16; m; m >>= 1) s += __shfl_xor(s, m);
    if (!l) o[r] = s;
}

// ---- K3: per-bin LDS counting-bucket build -> coalesced bucket/deg writes
__global__ __launch_bounds__(256) void k_build(const unsigned int* __restrict__ bins,
                                               const int* __restrict__ bcur,
                                               unsigned short* __restrict__ bucket,
                                               int* __restrict__ deg) {
    __shared__ int lcount[SPAN];
    __shared__ unsigned short lb[SPAN * LCAP];   // 12 KB
    int tid = threadIdx.x;
    int bin = blockIdx.x;
    int nodebase = bin * SPAN;
    int nnodes = min(SPAN, N_SYM - nodebase);
    for (int i = tid; i < SPAN; i += 256) lcount[i] = 0;
    __syncthreads();
    // half-wave (32 lanes) per sub-region: 8 parallel chains, ~2 subs each
    int hw = tid >> 5;          // 0..7
    int hl = tid & 31;
    for (int sub = hw; sub < SUBS; sub += 8) {
        int region = bin * SUBS + sub;
        int n = bcur[region * CURSTRIDE];
        if (n > SCAP) n = SCAP;
        const unsigned int* base = bins + region * SCAP;
        for (int i = hl; i < n; i += 32) {
            unsigned int v = base[i];
            int sl = v >> 14;
            int d = v & 0x3FFF;
            int rank = atomicAdd(&lcount[sl], 1);
            if (rank < LCAP) lb[sl * LCAP + rank] = (unsigned short)d;
        }
    }
    __syncthreads();
    for (int i = tid; i < nnodes; i += 256)
        deg[nodebase + i] = min(lcount[i], LCAP);
    // flat coalesced copy: lb -> bucket[nodebase*LCAP ..]
    unsigned int* gb = (unsigned int*)(bucket + nodebase * LCAP);
    const unsigned int* lbu = (const unsigned int*)lb;
    int words = nnodes * LCAP / 2;
    for (int i = tid; i < words; i += 256) gb[i] = lbu[i];
}

// ---- K4: per-node softmax + weighted gather: 32 lanes / node ----
__device__ __forceinline__ void acc_row(float4& acc, float2 rr, float ww) {
    __half2 a01 = *(__half2*)&rr.x;
    __half2 a23 = *(__half2*)&rr.y;
    float2 f01 = __half22float2(a01), f23 = __half22float2(a23);
    acc.x += ww * f01.x;
    acc.y += ww * f01.y;
    acc.z += ww * f23.x;
    acc.w += ww * f23.y;
}

__global__ __launch_bounds__(256) void k_agg(const int* __restrict__ deg,
                                             const unsigned short* __restrict__ bucket,
                                             const float* __restrict__ al2,
                                             const float* __restrict__ ar2,
                                             const __half* __restrict__ h16,
                                             const float* __restrict__ b,
                                             __half* __restrict__ hout) {
    int node = (blockIdx.x * 256 + threadIdx.x) >> 5;
    int l = threadIdx.x & 31;
    if (node >= N_SYM) return;
    int dg = deg[node];            // already clamped <= LCAP
    int off = node * LCAP;
    float arn = ar2[node];
    // lane l caches edge l's (dis, logit) in registers (coalesced load)
    int di = 0;
    float lv = -1e30f;
    if (l < dg) {
        di = bucket[off + l];
        float t = al2[di] + arn;
        lv = (t > 0.f) ? t : NEG_SLOPE * t;
    }
    float mm = lv;
    for (int i = 32 + l; i < dg; i += 32) {        // rare tail (dg in 33..48)
        float t = al2[bucket[off + i]] + arn;
        t = (t > 0.f) ? t : NEG_SLOPE * t;
        mm = fmaxf(mm, t);
    }
#pragma unroll
    for (int s = 16; s; s >>= 1) mm = fmaxf(mm, __shfl_xor(mm, s, 32));

    const float2* hb = (const float2*)h16;   // row d -> units d*32 + l
    float4 acc = make_float4(0.f, 0.f, 0.f, 0.f);
    float den = 0.f;                          // w lane-uniform: no reduce needed
    int dgc = dg < 32 ? dg : 32;
    int e = 0;
    for (; e + 4 <= dgc; e += 4) {
        int d0 = __shfl(di, e + 0, 32); float w0 = __expf(__shfl(lv, e + 0, 32) - mm);
        int d1 = __shfl(di, e + 1, 32); float w1 = __expf(__shfl(lv, e + 1, 32) - mm);
        int d2 = __shfl(di, e + 2, 32); float w2 = __expf(__shfl(lv, e + 2, 32) - mm);
        int d3 = __shfl(di, e + 3, 32); float w3 = __expf(__shfl(lv, e + 3, 32) - mm);
        float2 r0 = hb[d0 * 32 + l];
        float2 r1 = hb[d1 * 32 + l];
        float2 r2 = hb[d2 * 32 + l];
        float2 r3 = hb[d3 * 32 + l];
        den += w0 + w1 + w2 + w3;
        acc_row(acc, r0, w0);
        acc_row(acc, r1, w1);
        acc_row(acc, r2, w2);
        acc_row(acc, r3, w3);
    }
    for (; e < dgc; ++e) {
        int d = __shfl(di, e, 32);
        float w = __expf(__shfl(lv, e, 32) - mm);
        float2 r = hb[d * 32 + l];
        den += w;
        acc_row(acc, r, w);
    }
    for (int i = 32; i < dg; ++i) {               // rare tail (dg in 33..48)
        int dd = bucket[off + i];
        float t = al2[dd] + arn;
        t = (t > 0.f) ? t : NEG_SLOPE * t;
        float w = __expf(t - mm);
        float2 r = hb[dd * 32 + l];
        den += w;
        acc_row(acc, r, w);
    }
    float inv = (dg > 0) ? 1.f / den : 0.f;
    float4 bv = *(const float4*)(b + l * 4);
    __half2 o01 = __floats2half2_rn(fmaxf(acc.x * inv + bv.x, 0.f),
                                    fmaxf(acc.y * inv + bv.y, 0.f));
    __half2 o23 = __floats2half2_rn(fmaxf(acc.z * inv + bv.z, 0.f),
                                    fmaxf(acc.w * inv + bv.w, 0.f));
    float2 pack;
    *(__half2*)&pack.x = o01;
    *(__half2*)&pack.y = o23;
    *(float2*)((__half2*)hout + node * 64 + 2 * l) = pack;
}

// ---- out = h_sym(fp16) @ lin_W + lin_b via MFMA f16: 64 rows/block, 4 waves ----
__global__ __launch_bounds__(256) void k_final(const __half* __restrict__ h,
                                               const float* __restrict__ W,
                                               const float* __restrict__ b,
                                               float* __restrict__ out) {
    // W^T staged fp16, row stride 136 halves = 272 B (16B-aligned, 2-way bank max)
    __shared__ __align__(16) _Float16 BT[64][136];
    __shared__ float bias[64];
    int tid = threadIdx.x;
    for (int idx = tid; idx < HID * OUTF; idx += 256) {
        int k = idx >> 6, c = idx & 63;
        BT[c][k] = (_Float16)W[idx];
    }
    if (tid < 64) bias[tid] = b[tid];
    __syncthreads();
    int wave = tid >> 6, lane = tid & 63;
    int rowbase = blockIdx.x * 64 + wave * 16;
    int arow = rowbase + (lane & 15);
    if (arow >= N_SYM) arow = N_SYM - 1;          // clamp reads; stores guarded
    int kbase = (lane >> 4) * 8;
    const _Float16* hp = (const _Float16*)h;
    f16x8 a[4];
#pragma unroll
    for (int kc = 0; kc < 4; ++kc)
        a[kc] = *(const f16x8*)(hp + arow * HID + kc * 32 + kbase);
#pragma unroll
    for (int ct = 0; ct < 4; ++ct) {
        int bcol = ct * 16 + (lane & 15);
        f32x4 acc = {0.f, 0.f, 0.f, 0.f};
#pragma unroll
        for (int kc = 0; kc < 4; ++kc) {
            f16x8 bf = *(const f16x8*)(&BT[bcol][kc * 32 + kbase]);
            acc = __builtin_amdgcn_mfma_f32_16x16x32_f16(a[kc], bf, acc, 0, 0, 0);
        }
        int r0 = rowbase + (lane >> 4) * 4;
        float bc = bias[bcol];
#pragma unroll
        for (int r = 0; r < 4; ++r) {
            int row = r0 + r;
            if (row < N_SYM) out[row * OUTF + bcol] = acc[r] + bc;
        }
    }
}

extern "C" void kernel_launch(void* const* d_in, const int* in_sizes, int n_in,
                              void* d_out, int out_size, void* d_ws, size_t ws_size,
                              hipStream_t stream) {
    const float* x_sym   = (const float*)d_in[0];
    const float* x_dis   = (const float*)d_in[1];
    const int*   esrc    = (const int*)d_in[2];
    const int*   edst    = (const int*)d_in[3];
    // d_in[4..8] = sym->dis GAT params: DEAD CODE (h_dis never used)
    const float* Wsrc_ds = (const float*)d_in[9];
    const float* Wdst_ds = (const float*)d_in[10];
    const float* asrc_ds = (const float*)d_in[11];
    const float* adst_ds = (const float*)d_in[12];
    const float* b_ds    = (const float*)d_in[13];
    const float* lin_W   = (const float*)d_in[14];
    const float* lin_b   = (const float*)d_in[15];
    float* out = (float*)d_out;

    // workspace layout (~26 MB)
    float*  ws     = (float*)d_ws;
    float*  v_dst  = ws;                      // 128
    float*  al2    = v_dst + 128;             // N_DIS
    float*  ar2    = al2 + N_DIS;             // N_SYM
    int*    deg    = (int*)(ar2 + N_SYM);     // N_SYM
    int*    bcur   = deg + N_SYM;             // NREG*CURSTRIDE = 100096 ints (400KB)
    unsigned int*   bins   = (unsigned int*)(bcur + NREG * CURSTRIDE); // NREG*SCAP (4.8MB)
    unsigned short* bucket = (unsigned short*)(bins + NREG * SCAP);    // N_SYM*LCAP (4.8MB)
    __half* h16    = (__half*)(bucket + N_SYM * LCAP);                 // N_DIS*HID (2.56MB)
    __half* h_sym  = h16 + N_DIS * HID;       // N_SYM*HID halves (12.8MB)

    k_proj<<<626, 256, 0, stream>>>(x_dis, Wsrc_ds, asrc_ds, Wdst_ds, adst_ds,
                                    h16, al2, v_dst, bcur);
    k_ar<<<N_SYM * 32 / 256, 256, 0, stream>>>(x_sym, v_dst, ar2, esrc, edst,
                                               bcur, bins);
    k_build<<<NB, 256, 0, stream>>>(bins, bcur, bucket, deg);
    k_agg<<<N_SYM * 32 / 256, 256, 0, stream>>>(deg, bucket, al2, ar2, h16,
                                                b_ds, h_sym);
    k_final<<<(N_SYM + 63) / 64, 256, 0, stream>>>(h_sym, lin_W, lin_b, out);
}